// Round 8
// baseline (468.881 us; speedup 1.0000x reference)
//
#include <hip/hip_runtime.h>
#include <hip/hip_bf16.h>
#include <cstdint>
#include <cstddef>

typedef __hip_bfloat16 bf16;
typedef __attribute__((ext_vector_type(8))) short bfrag8;   // 8 bf16 = 4 VGPR
typedef __attribute__((ext_vector_type(4))) float f32x4;    // MFMA acc

// ---- bf16 bit helpers ------------------------------------------------------
__device__ __forceinline__ float bfu2f(unsigned int u16) {
    unsigned int w = u16 << 16;
    float f; __builtin_memcpy(&f, &w, 4); return f;
}
__device__ __forceinline__ unsigned short f2bfu(float f) {
    bf16 h = __float2bfloat16(f);
    unsigned short u; __builtin_memcpy(&u, &h, 2); return u;
}
__device__ __forceinline__ void unpk8(const uint4 u, float* f) {
    f[0] = bfu2f(u.x & 0xffffu); f[1] = bfu2f(u.x >> 16);
    f[2] = bfu2f(u.y & 0xffffu); f[3] = bfu2f(u.y >> 16);
    f[4] = bfu2f(u.z & 0xffffu); f[5] = bfu2f(u.z >> 16);
    f[6] = bfu2f(u.w & 0xffffu); f[7] = bfu2f(u.w >> 16);
}

// ---------------------------------------------------------------------------
// Weight prep: OIHW f32 -> MFMA A-fragment bf16 layout (3x3 convs).
// ---------------------------------------------------------------------------
struct WSrc { const float* w[9]; };

__global__ __launch_bounds__(256) void prep_k(WSrc src, bf16* __restrict__ wp) {
    const int l = blockIdx.x;
    const int CI[9]  = {16, 16, 16, 32, 32, 32, 32, 16, 16};
    const int CO[9]  = {16, 16, 32, 32, 32, 32, 16, 16, 16};
    const int OFF[9] = {0, 3072, 6144, 12288, 21504, 30720, 39936, 44544, 47616};
    const int cin = CI[l], cout = CO[l], nct = cout / 16;
    const int nt = (cin == 32) ? 9 : 6;
    const int sz = nt * nct * 512;
    const float* w = src.w[l];
    bf16* dst = wp + OFF[l];
    for (int e = threadIdx.x; e < sz; e += 256) {
        const int j = e & 7;
        const int lane = (e >> 3) & 63;
        const int r = e >> 9;
        const int ct = r % nct, tp = r / nct;
        const int co = ct * 16 + (lane & 15);
        const int kk = ((lane >> 4) << 3) + j;
        float v;
        if (cin == 32) {
            const int ci = kk, ky = tp / 3, kx = tp % 3;
            v = w[((co * 32 + ci) * 3 + ky) * 3 + kx];
        } else {
            const int ci = kk & 15, dxs = kk >> 4;
            const int ky = tp >> 1, kx = (tp & 1) * 2 + dxs;
            v = (kx < 3) ? w[((co * 16 + ci) * 3 + ky) * 3 + kx] : 0.0f;
        }
        dst[e] = __float2bfloat16(v);
    }
}

// ---------------------------------------------------------------------------
// ConvT weight prep: wt[ci][co][a][b] f32 -> A-fragment bf16, m = co*4+ab.
// ---------------------------------------------------------------------------
__global__ __launch_bounds__(256) void prep2_k(
    const float* __restrict__ wt, bf16* __restrict__ wpT)
{
    for (int e = threadIdx.x; e < 4096; e += 256) {
        const int j = e & 7;
        const int lane = (e >> 3) & 63;
        const int mt = e >> 9;
        const int m = mt * 16 + (lane & 15);
        const int k = ((lane >> 4) << 3) + j;     // ci
        wpT[e] = __float2bfloat16(wt[k * 128 + m]);   // m = co*4 + a*2 + b
    }
}

// ---------------------------------------------------------------------------
// x (NCHW f32, 16ch) -> NHWC bf16
// ---------------------------------------------------------------------------
__global__ __launch_bounds__(256) void xtonhwc_k(
    const float* __restrict__ x, bf16* __restrict__ xh)
{
    const int idx = blockIdx.x * 256 + threadIdx.x;   // 4*262144
    const int n = idx >> 18, px = idx & 262143;
    const float* xp = x + (size_t)n * 16 * 262144 + px;
    unsigned short r[16];
    #pragma unroll
    for (int c = 0; c < 16; ++c) r[c] = f2bfu(xp[(size_t)c * 262144]);
    __builtin_memcpy(xh + (size_t)idx * 16, r, 32);
}

// ---------------------------------------------------------------------------
// Implicit-GEMM 3x3 SAME conv with MFMA 16x16x32 bf16, NHWC (unchanged).
// ---------------------------------------------------------------------------
template<int CIN, int COUT, bool RELU, int LW>
__global__ __launch_bounds__(256) void convm_k(
    const bf16* __restrict__ in, const bf16* __restrict__ wp,
    const float* __restrict__ bias, bf16* __restrict__ out)
{
    constexpr int Wd = 1 << LW;
    constexpr int PLANE = Wd * Wd;
    constexpr int NCT = COUT / 16;
    constexpr int NT = (CIN == 32) ? 9 : 6;
    constexpr int CB = CIN * 2;

    const int lane = threadIdx.x & 63;
    const int l4 = lane >> 4;
    const int lm = lane & 15;
    const int wv = threadIdx.x >> 6;
    const int n = blockIdx.y;
    const int pxb = blockIdx.x * 256 + wv * 64;
    const int y = pxb >> LW;
    const int xw = pxb & (Wd - 1);

    bfrag8 afr[NT][NCT];
    #pragma unroll
    for (int tp = 0; tp < NT; ++tp)
        #pragma unroll
        for (int ct = 0; ct < NCT; ++ct)
            __builtin_memcpy(&afr[tp][ct],
                wp + ((size_t)(tp * NCT + ct) * 64 + lane) * 8, 16);

    f32x4 acc[4][NCT];
    #pragma unroll
    for (int ct = 0; ct < NCT; ++ct) {
        const float4 bv = *reinterpret_cast<const float4*>(bias + ct * 16 + l4 * 4);
        #pragma unroll
        for (int t = 0; t < 4; ++t) {
            acc[t][ct][0] = bv.x; acc[t][ct][1] = bv.y;
            acc[t][ct][2] = bv.z; acc[t][ct][3] = bv.w;
        }
    }

    bool okL[4], okR[4];
    #pragma unroll
    for (int t = 0; t < 4; ++t) {
        const int xl = xw + t * 16 + lm;
        okL[t] = (xl != 0)      || (CIN == 16 && lane >= 32);
        okR[t] = (xl != Wd - 1) || (CIN == 16 && lane >= 32);
    }

    int laneoff;
    if (CIN == 32) laneoff = lm * 64 + l4 * 16;
    else           laneoff = lm * 32 + (l4 >> 1) * 32 + (l4 & 1) * 16;

    const char* base = (const char*)in
        + ((size_t)n * PLANE + (size_t)y * Wd + xw) * CB + laneoff;

    #pragma unroll
    for (int ky = 0; ky < 3; ++ky) {
        if ((unsigned)(y + ky - 1) >= (unsigned)Wd) continue;
        const char* rb = base + (ky - 1) * Wd * CB;
        if (CIN == 32) {
            #pragma unroll
            for (int dx = 0; dx < 3; ++dx) {
                #pragma unroll
                for (int t = 0; t < 4; ++t) {
                    uint4 u = *reinterpret_cast<const uint4*>(rb + ((dx - 1) + t * 16) * 64);
                    if (dx == 0 && !okL[t]) { u.x = 0; u.y = 0; u.z = 0; u.w = 0; }
                    if (dx == 2 && !okR[t]) { u.x = 0; u.y = 0; u.z = 0; u.w = 0; }
                    bfrag8 b; __builtin_memcpy(&b, &u, 16);
                    #pragma unroll
                    for (int ct = 0; ct < NCT; ++ct)
                        acc[t][ct] = __builtin_amdgcn_mfma_f32_16x16x32_bf16(
                            afr[ky * 3 + dx][ct], b, acc[t][ct], 0, 0, 0);
                }
            }
        } else {
            #pragma unroll
            for (int p = 0; p < 2; ++p) {
                #pragma unroll
                for (int t = 0; t < 4; ++t) {
                    uint4 u = *reinterpret_cast<const uint4*>(rb + (p ? 32 : -32) + t * 512);
                    if (p == 0 && !okL[t]) { u.x = 0; u.y = 0; u.z = 0; u.w = 0; }
                    if (p == 1 && !okR[t]) { u.x = 0; u.y = 0; u.z = 0; u.w = 0; }
                    bfrag8 b; __builtin_memcpy(&b, &u, 16);
                    #pragma unroll
                    for (int ct = 0; ct < NCT; ++ct)
                        acc[t][ct] = __builtin_amdgcn_mfma_f32_16x16x32_bf16(
                            afr[ky * 2 + p][ct], b, acc[t][ct], 0, 0, 0);
                }
            }
        }
    }

    char* ob = (char*)out + ((size_t)n * PLANE + (size_t)y * Wd + xw) * (COUT * 2);
    #pragma unroll
    for (int t = 0; t < 4; ++t)
        #pragma unroll
        for (int ct = 0; ct < NCT; ++ct) {
            float a0 = acc[t][ct][0], a1 = acc[t][ct][1];
            float a2 = acc[t][ct][2], a3 = acc[t][ct][3];
            if (RELU) {
                a0 = fmaxf(a0, 0.f); a1 = fmaxf(a1, 0.f);
                a2 = fmaxf(a2, 0.f); a3 = fmaxf(a3, 0.f);
            }
            ushort4 pk;
            pk.x = f2bfu(a0); pk.y = f2bfu(a1); pk.z = f2bfu(a2); pk.w = f2bfu(a3);
            *reinterpret_cast<ushort4*>(
                ob + ((size_t)(t * 16 + lm) * COUT + ct * 16 + l4 * 4) * 2) = pk;
        }
}

// ---------------------------------------------------------------------------
// 2x2 maxpool NHWC 32ch (unchanged).
// ---------------------------------------------------------------------------
__global__ __launch_bounds__(256) void pool_k(
    const bf16* __restrict__ in, bf16* __restrict__ out)
{
    const int idx = blockIdx.x * 256 + threadIdx.x;
    const int c8 = (idx & 3) * 8;
    const int opx = idx >> 2;
    const int n = opx >> 16;
    const int p = opx & 65535;
    const int oy = p >> 8, ox = p & 255;
    const char* ip = (const char*)in
        + (((size_t)n * 262144 + (size_t)(2 * oy) * 512 + 2 * ox) * 32 + c8) * 2;
    uint4 ua = *reinterpret_cast<const uint4*>(ip);
    uint4 ub = *reinterpret_cast<const uint4*>(ip + 64);
    uint4 uc = *reinterpret_cast<const uint4*>(ip + 512 * 64);
    uint4 ud = *reinterpret_cast<const uint4*>(ip + 512 * 64 + 64);
    float a[8], b[8], c[8], d[8];
    unpk8(ua, a); unpk8(ub, b); unpk8(uc, c); unpk8(ud, d);
    unsigned short r[8];
    #pragma unroll
    for (int k = 0; k < 8; ++k)
        r[k] = f2bfu(fmaxf(fmaxf(a[k], b[k]), fmaxf(c[k], d[k])));
    __builtin_memcpy((char*)out + (((size_t)n * 65536 + p) * 32 + c8) * 2, r, 16);
}

// ---------------------------------------------------------------------------
// ConvT 2x2 s2 + skip add via MFMA (unchanged, R6).
// ---------------------------------------------------------------------------
__global__ __launch_bounds__(256) void convTm_k(
    const bf16* __restrict__ e, const bf16* __restrict__ wpT,
    const float* __restrict__ bt, bf16* __restrict__ du)
{
    __shared__ float lds[4][16 * 132];
    const int lane = threadIdx.x & 63;
    const int wv = threadIdx.x >> 6;
    const int l4 = lane >> 4, lm = lane & 15;
    const int n = blockIdx.y;
    const int row = blockIdx.x;
    const int j0 = wv * 64;

    bfrag8 afr[8];
    #pragma unroll
    for (int mt = 0; mt < 8; ++mt)
        __builtin_memcpy(&afr[mt], wpT + ((size_t)(mt * 64 + lane)) * 8, 16);

    float bco[8];
    #pragma unroll
    for (int mt = 0; mt < 8; ++mt) bco[mt] = bt[mt * 4 + l4];

    const char* ep = (const char*)e + ((size_t)n * 65536 + (size_t)row * 256 + j0) * 64;
    float* L = lds[wv];

    const int ra = lane >> 5;
    const int ru = lane & 31;
    const int rj = ru >> 1;
    const int rb = ru & 1;

    #pragma unroll 1
    for (int nt = 0; nt < 4; ++nt) {
        bfrag8 bf;
        __builtin_memcpy(&bf, ep + (nt * 16 + lm) * 64 + l4 * 16, 16);

        #pragma unroll
        for (int mt = 0; mt < 8; ++mt) {
            f32x4 acc;
            acc[0] = bco[mt]; acc[1] = bco[mt]; acc[2] = bco[mt]; acc[3] = bco[mt];
            acc = __builtin_amdgcn_mfma_f32_16x16x32_bf16(afr[mt], bf, acc, 0, 0, 0);
            float4 st; st.x = acc[0]; st.y = acc[1]; st.z = acc[2]; st.w = acc[3];
            *reinterpret_cast<float4*>(L + lm * 132 + mt * 16 + l4 * 4) = st;
        }
        __syncthreads();

        {
            const float* Ls = L + rj * 132 + ra * 2 + rb;
            char* dp = (char*)du
                + (((size_t)n * 262144
                    + (size_t)(2 * row + ra) * 512
                    + (size_t)(2 * (j0 + nt * 16 + rj) + rb)) * 32) * 2;
            float add[32];
            #pragma unroll
            for (int co = 0; co < 32; ++co) add[co] = Ls[co * 4];
            #pragma unroll
            for (int q = 0; q < 4; ++q) {
                uint4 u = *reinterpret_cast<const uint4*>(dp + q * 16);
                float dv[8]; unpk8(u, dv);
                unsigned short r[8];
                #pragma unroll
                for (int k = 0; k < 8; ++k) r[k] = f2bfu(dv[k] + add[q * 8 + k]);
                __builtin_memcpy(dp + q * 16, r, 16);
            }
        }
        __syncthreads();
    }
}

// ---------------------------------------------------------------------------
// Pack pass: xn[px][12] f32 = { x ch 0..10 , S }, px-major (48 B/px).
// S(p) = sum_i cw_i * v_i(p)^2 over the 27 combined channels.
// ---------------------------------------------------------------------------
__global__ __launch_bounds__(256) void pack_k(
    const float* __restrict__ xin, const bf16* __restrict__ feats,
    const float* __restrict__ fp, float* __restrict__ xn)
{
    constexpr int PLANE = 512 * 512;
    const int pix = blockIdx.x * 256 + threadIdx.x;
    const int n = blockIdx.y;

    const float* xb = xin + (size_t)n * 16 * PLANE + pix;
    const char* fb = (const char*)feats + ((size_t)n * PLANE + pix) * 32;

    float v[12];
    float s = 0.0f;
    #pragma unroll
    for (int i = 0; i < 11; ++i) {
        v[i] = xb[(size_t)i * PLANE];
        s = fmaf(fp[i], v[i] * v[i], s);
    }
    uint4 u0 = *reinterpret_cast<const uint4*>(fb);
    uint4 u1 = *reinterpret_cast<const uint4*>(fb + 16);
    float fv[16];
    unpk8(u0, fv); unpk8(u1, fv + 8);
    #pragma unroll
    for (int i = 0; i < 16; ++i)
        s = fmaf(fp[11 + i], fv[i] * fv[i], s);
    v[11] = s;

    float* op = xn + ((size_t)n * PLANE + pix) * 12;
    *reinterpret_cast<float4*>(op)     = make_float4(v[0], v[1], v[2],  v[3]);
    *reinterpret_cast<float4*>(op + 4) = make_float4(v[4], v[5], v[6],  v[7]);
    *reinterpret_cast<float4*>(op + 8) = make_float4(v[8], v[9], v[10], v[11]);
}

// ---------------------------------------------------------------------------
// Bilateral, factored + packed:
//   logw(p,q) = S_q - 2 * sum_i g_i(p) v_i(q) + S_p + spatial
// xn[px][12] = {x0..x10, S} (3x16B loads); feats NHWC bf16 (2x16B loads).
// 5 loads per tap, all px-major.
// ---------------------------------------------------------------------------
__global__ __launch_bounds__(256) void bil_k(
    const float* __restrict__ xn, const bf16* __restrict__ feats,
    const float* __restrict__ fp, float* __restrict__ out)
{
    constexpr int PLANE = 512 * 512;
    const int pix = blockIdx.x * 256 + threadIdx.x;
    const int n = blockIdx.y;
    const int y = pix >> 9, xx = pix & 511;

    const float sy = fp[27], sx = fp[28];

    const float* xb = xn + ((size_t)n * PLANE + pix) * 12;
    const char* fb = (const char*)feats + ((size_t)n * PLANE + pix) * 32;

    // center: g = cw*c, Sp = packed S
    float g[27];
    float Sp;
    {
        const float4 c0 = *reinterpret_cast<const float4*>(xb);
        const float4 c1 = *reinterpret_cast<const float4*>(xb + 4);
        const float4 c2 = *reinterpret_cast<const float4*>(xb + 8);
        const float cc[12] = {c0.x, c0.y, c0.z, c0.w, c1.x, c1.y, c1.z, c1.w,
                              c2.x, c2.y, c2.z, c2.w};
        #pragma unroll
        for (int i = 0; i < 11; ++i) g[i] = fp[i] * cc[i];
        Sp = cc[11];
        uint4 u0 = *reinterpret_cast<const uint4*>(fb);
        uint4 u1 = *reinterpret_cast<const uint4*>(fb + 16);
        float cf[16];
        unpk8(u0, cf); unpk8(u1, cf + 8);
        #pragma unroll
        for (int i = 0; i < 16; ++i) g[11 + i] = fp[11 + i] * cf[i];
    }

    float num[11];
    #pragma unroll
    for (int i = 0; i < 11; ++i) num[i] = 0.0f;
    float den = 0.0f;

    #pragma unroll
    for (int dy = -2; dy <= 2; ++dy) {
        const int yy = y + 2 * dy;
        if ((unsigned)yy > 511u) continue;            // uniform per block
        const float baseY = fmaf(sy, (float)(4 * dy * dy), Sp);
        #pragma unroll
        for (int dx = -2; dx <= 2; ++dx) {
            const int xv = xx + 2 * dx;
            if ((unsigned)xv > 511u) continue;        // edge lanes only
            const int off = dy * 1024 + dx * 2;

            const float* xq = xb + (ptrdiff_t)off * 12;
            const float4 s0 = *reinterpret_cast<const float4*>(xq);
            const float4 s1 = *reinterpret_cast<const float4*>(xq + 4);
            const float4 s2 = *reinterpret_cast<const float4*>(xq + 8);
            const float sv[12] = {s0.x, s0.y, s0.z, s0.w, s1.x, s1.y, s1.z, s1.w,
                                  s2.x, s2.y, s2.z, s2.w};

            float base = fmaf(sx, (float)(4 * dx * dx), baseY) + sv[11];

            float cross = g[0] * sv[0];
            #pragma unroll
            for (int i = 1; i < 11; ++i) cross = fmaf(g[i], sv[i], cross);

            const char* fq = fb + (ptrdiff_t)off * 32;
            uint4 u0 = *reinterpret_cast<const uint4*>(fq);
            uint4 u1 = *reinterpret_cast<const uint4*>(fq + 16);
            float fv[16];
            unpk8(u0, fv); unpk8(u1, fv + 8);
            #pragma unroll
            for (int i = 0; i < 16; ++i)
                cross = fmaf(g[11 + i], fv[i], cross);

            const float w = __expf(fmaf(-2.0f, cross, base));
            #pragma unroll
            for (int i = 0; i < 11; ++i) num[i] = fmaf(w, sv[i], num[i]);
            den += w;
        }
    }

    const float inv = 1.0f / den;
    float* ob = out + (size_t)n * 11 * PLANE + pix;
    #pragma unroll
    for (int i = 0; i < 11; ++i) ob[(size_t)i * PLANE] = num[i] * inv;
}

// ---------------------------------------------------------------------------
extern "C" void kernel_launch(void* const* d_in, const int* in_sizes, int n_in,
                              void* d_out, int out_size, void* d_ws, size_t ws_size,
                              hipStream_t stream)
{
    const float* x = (const float*)d_in[0];
    const float* Wv[9];
    const float* Bv[9];
    if (in_sizes[2] == 16) {
        for (int i = 0; i < 9; ++i) {
            Wv[i] = (const float*)d_in[1 + 2 * i];
            Bv[i] = (const float*)d_in[2 + 2 * i];
        }
    } else {
        for (int i = 0; i < 9; ++i) {
            Wv[i] = (const float*)d_in[1 + i];
            Bv[i] = (const float*)d_in[10 + i];
        }
    }
    const float* wt = (const float*)d_in[19];
    const float* bt = (const float*)d_in[20];
    const float* fp = (const float*)d_in[21];
    float* out = (float*)d_out;

    constexpr size_t MiB = 1ull << 20;
    char* ws = (char*)d_ws;

    bf16* wp  = (bf16*)(ws + 4096);
    bf16* wpT = (bf16*)(ws + 256 * 1024);
    bf16 *xh, *du, *bufA, *bufB;
    if (ws_size >= 165 * MiB) {
        xh   = (bf16*)(ws + 1 * MiB);
        du   = (bf16*)(ws + 34 * MiB);   // 64 MiB region
        bufA = (bf16*)(ws + 99 * MiB);
        bufB = (bf16*)(ws + 132 * MiB);
    } else if (ws_size >= 132 * MiB) {
        xh   = (bf16*)(ws + 1 * MiB);
        du   = (bf16*)(ws + 34 * MiB);
        bufA = (bf16*)(ws + 99 * MiB);
        bufB = xh;
    } else {
        xh   = (bf16*)((char*)d_out + 256);
        du   = (bf16*)(ws + 1 * MiB);    // 65 MiB region
        bufA = (bf16*)(ws + 66 * MiB);
        bufB = xh;
    }
    // du is dead after conv6 reads it; reuse its region for xn (48 MiB <= 64)
    float* xn = (float*)du;

    WSrc srcs;
    for (int i = 0; i < 9; ++i) srcs.w[i] = Wv[i];

    prep_k<<<9, 256, 0, stream>>>(srcs, wp);
    prep2_k<<<1, 256, 0, stream>>>(wt, wpT);
    xtonhwc_k<<<4096, 256, 0, stream>>>(x, xh);

    const dim3 blk(256);
    const dim3 g512(1024, 4), g256(256, 4);

    convm_k<16, 16, true,  9><<<g512, blk, 0, stream>>>(xh,   wp + 0,     Bv[0], bufA);
    convm_k<16, 16, true,  9><<<g512, blk, 0, stream>>>(bufA, wp + 3072,  Bv[1], bufB);
    convm_k<16, 32, false, 9><<<g512, blk, 0, stream>>>(bufB, wp + 6144,  Bv[2], du);

    pool_k<<<4096, blk, 0, stream>>>(du, bufA);
    convm_k<32, 32, true, 8><<<g256, blk, 0, stream>>>(bufA, wp + 12288, Bv[3], bufB);
    convm_k<32, 32, true, 8><<<g256, blk, 0, stream>>>(bufB, wp + 21504, Bv[4], bufA);
    convm_k<32, 32, true, 8><<<g256, blk, 0, stream>>>(bufA, wp + 30720, Bv[5], bufB);

    convTm_k<<<g256, blk, 0, stream>>>(bufB, wpT, bt, du);

    convm_k<32, 16, true,  9><<<g512, blk, 0, stream>>>(du,   wp + 39936, Bv[6], bufA);
    convm_k<16, 16, true,  9><<<g512, blk, 0, stream>>>(bufA, wp + 44544, Bv[7], bufB);
    convm_k<16, 16, false, 9><<<g512, blk, 0, stream>>>(bufB, wp + 47616, Bv[8], bufA);

    // pack x(11ch)+S px-major into xn (du region, dead now), then bilateral
    pack_k<<<g512, blk, 0, stream>>>(x, bufA, fp, xn);
    bil_k<<<g512, blk, 0, stream>>>(xn, bufA, fp, out);

    (void)n_in; (void)out_size;
}

// Round 9
// 436.445 us; speedup vs baseline: 1.0743x; 1.0743x over previous
//
#include <hip/hip_runtime.h>
#include <hip/hip_bf16.h>
#include <cstdint>
#include <cstddef>

typedef __hip_bfloat16 bf16;
typedef __attribute__((ext_vector_type(8))) short bfrag8;   // 8 bf16 = 4 VGPR
typedef __attribute__((ext_vector_type(4))) float f32x4;    // MFMA acc

// ---- bf16 bit helpers ------------------------------------------------------
__device__ __forceinline__ float bfu2f(unsigned int u16) {
    unsigned int w = u16 << 16;
    float f; __builtin_memcpy(&f, &w, 4); return f;
}
__device__ __forceinline__ float bfhi2f(unsigned int u) {      // high half as-is
    unsigned int w = u & 0xffff0000u;
    float f; __builtin_memcpy(&f, &w, 4); return f;
}
__device__ __forceinline__ unsigned short f2bfu(float f) {
    bf16 h = __float2bfloat16(f);
    unsigned short u; __builtin_memcpy(&u, &h, 2); return u;
}
__device__ __forceinline__ void unpk8(const uint4 u, float* f) {
    f[0] = bfu2f(u.x); f[1] = bfhi2f(u.x);
    f[2] = bfu2f(u.y); f[3] = bfhi2f(u.y);
    f[4] = bfu2f(u.z); f[5] = bfhi2f(u.z);
    f[6] = bfu2f(u.w); f[7] = bfhi2f(u.w);
}

// ---------------------------------------------------------------------------
// Weight prep: OIHW f32 -> MFMA A-fragment bf16 (blocks 0..8 = convs,
// block 9 = convT weights, m = co*4 + a*2 + b, k = ci).
// ---------------------------------------------------------------------------
struct WSrc { const float* w[10]; };

__global__ __launch_bounds__(256) void prep_k(WSrc src, bf16* __restrict__ wp,
                                              bf16* __restrict__ wpT) {
    const int l = blockIdx.x;
    if (l == 9) {
        const float* wt = src.w[9];
        for (int e = threadIdx.x; e < 4096; e += 256) {
            const int j = e & 7;
            const int lane = (e >> 3) & 63;
            const int mt = e >> 9;
            const int m = mt * 16 + (lane & 15);
            const int k = ((lane >> 4) << 3) + j;     // ci
            wpT[e] = __float2bfloat16(wt[k * 128 + m]);
        }
        return;
    }
    const int CI[9]  = {16, 16, 16, 32, 32, 32, 32, 16, 16};
    const int CO[9]  = {16, 16, 32, 32, 32, 32, 16, 16, 16};
    const int OFF[9] = {0, 3072, 6144, 12288, 21504, 30720, 39936, 44544, 47616};
    const int cin = CI[l], cout = CO[l], nct = cout / 16;
    const int nt = (cin == 32) ? 9 : 6;
    const int sz = nt * nct * 512;
    const float* w = src.w[l];
    bf16* dst = wp + OFF[l];
    for (int e = threadIdx.x; e < sz; e += 256) {
        const int j = e & 7;
        const int lane = (e >> 3) & 63;
        const int r = e >> 9;
        const int ct = r % nct, tp = r / nct;
        const int co = ct * 16 + (lane & 15);
        const int kk = ((lane >> 4) << 3) + j;
        float v;
        if (cin == 32) {
            const int ci = kk, ky = tp / 3, kx = tp % 3;
            v = w[((co * 32 + ci) * 3 + ky) * 3 + kx];
        } else {
            const int ci = kk & 15, dxs = kk >> 4;
            const int ky = tp >> 1, kx = (tp & 1) * 2 + dxs;
            v = (kx < 3) ? w[((co * 16 + ci) * 3 + ky) * 3 + kx] : 0.0f;
        }
        dst[e] = __float2bfloat16(v);
    }
}

// ---------------------------------------------------------------------------
// x (NCHW f32, 16ch) -> NHWC bf16
// ---------------------------------------------------------------------------
__global__ __launch_bounds__(256) void xtonhwc_k(
    const float* __restrict__ x, bf16* __restrict__ xh)
{
    const int idx = blockIdx.x * 256 + threadIdx.x;   // 4*262144
    const int n = idx >> 18, px = idx & 262143;
    const float* xp = x + (size_t)n * 16 * 262144 + px;
    unsigned short r[16];
    #pragma unroll
    for (int c = 0; c < 16; ++c) r[c] = f2bfu(xp[(size_t)c * 262144]);
    __builtin_memcpy(xh + (size_t)idx * 16, r, 32);
}

// ---------------------------------------------------------------------------
// Implicit-GEMM 3x3 SAME conv with MFMA 16x16x32 bf16, NHWC (unchanged).
// ---------------------------------------------------------------------------
template<int CIN, int COUT, bool RELU, int LW>
__global__ __launch_bounds__(256) void convm_k(
    const bf16* __restrict__ in, const bf16* __restrict__ wp,
    const float* __restrict__ bias, bf16* __restrict__ out)
{
    constexpr int Wd = 1 << LW;
    constexpr int PLANE = Wd * Wd;
    constexpr int NCT = COUT / 16;
    constexpr int NT = (CIN == 32) ? 9 : 6;
    constexpr int CB = CIN * 2;

    const int lane = threadIdx.x & 63;
    const int l4 = lane >> 4;
    const int lm = lane & 15;
    const int wv = threadIdx.x >> 6;
    const int n = blockIdx.y;
    const int pxb = blockIdx.x * 256 + wv * 64;
    const int y = pxb >> LW;
    const int xw = pxb & (Wd - 1);

    bfrag8 afr[NT][NCT];
    #pragma unroll
    for (int tp = 0; tp < NT; ++tp)
        #pragma unroll
        for (int ct = 0; ct < NCT; ++ct)
            __builtin_memcpy(&afr[tp][ct],
                wp + ((size_t)(tp * NCT + ct) * 64 + lane) * 8, 16);

    f32x4 acc[4][NCT];
    #pragma unroll
    for (int ct = 0; ct < NCT; ++ct) {
        const float4 bv = *reinterpret_cast<const float4*>(bias + ct * 16 + l4 * 4);
        #pragma unroll
        for (int t = 0; t < 4; ++t) {
            acc[t][ct][0] = bv.x; acc[t][ct][1] = bv.y;
            acc[t][ct][2] = bv.z; acc[t][ct][3] = bv.w;
        }
    }

    bool okL[4], okR[4];
    #pragma unroll
    for (int t = 0; t < 4; ++t) {
        const int xl = xw + t * 16 + lm;
        okL[t] = (xl != 0)      || (CIN == 16 && lane >= 32);
        okR[t] = (xl != Wd - 1) || (CIN == 16 && lane >= 32);
    }

    int laneoff;
    if (CIN == 32) laneoff = lm * 64 + l4 * 16;
    else           laneoff = lm * 32 + (l4 >> 1) * 32 + (l4 & 1) * 16;

    const char* base = (const char*)in
        + ((size_t)n * PLANE + (size_t)y * Wd + xw) * CB + laneoff;

    #pragma unroll
    for (int ky = 0; ky < 3; ++ky) {
        if ((unsigned)(y + ky - 1) >= (unsigned)Wd) continue;
        const char* rb = base + (ky - 1) * Wd * CB;
        if (CIN == 32) {
            #pragma unroll
            for (int dx = 0; dx < 3; ++dx) {
                #pragma unroll
                for (int t = 0; t < 4; ++t) {
                    uint4 u = *reinterpret_cast<const uint4*>(rb + ((dx - 1) + t * 16) * 64);
                    if (dx == 0 && !okL[t]) { u.x = 0; u.y = 0; u.z = 0; u.w = 0; }
                    if (dx == 2 && !okR[t]) { u.x = 0; u.y = 0; u.z = 0; u.w = 0; }
                    bfrag8 b; __builtin_memcpy(&b, &u, 16);
                    #pragma unroll
                    for (int ct = 0; ct < NCT; ++ct)
                        acc[t][ct] = __builtin_amdgcn_mfma_f32_16x16x32_bf16(
                            afr[ky * 3 + dx][ct], b, acc[t][ct], 0, 0, 0);
                }
            }
        } else {
            #pragma unroll
            for (int p = 0; p < 2; ++p) {
                #pragma unroll
                for (int t = 0; t < 4; ++t) {
                    uint4 u = *reinterpret_cast<const uint4*>(rb + (p ? 32 : -32) + t * 512);
                    if (p == 0 && !okL[t]) { u.x = 0; u.y = 0; u.z = 0; u.w = 0; }
                    if (p == 1 && !okR[t]) { u.x = 0; u.y = 0; u.z = 0; u.w = 0; }
                    bfrag8 b; __builtin_memcpy(&b, &u, 16);
                    #pragma unroll
                    for (int ct = 0; ct < NCT; ++ct)
                        acc[t][ct] = __builtin_amdgcn_mfma_f32_16x16x32_bf16(
                            afr[ky * 2 + p][ct], b, acc[t][ct], 0, 0, 0);
                }
            }
        }
    }

    char* ob = (char*)out + ((size_t)n * PLANE + (size_t)y * Wd + xw) * (COUT * 2);
    #pragma unroll
    for (int t = 0; t < 4; ++t)
        #pragma unroll
        for (int ct = 0; ct < NCT; ++ct) {
            float a0 = acc[t][ct][0], a1 = acc[t][ct][1];
            float a2 = acc[t][ct][2], a3 = acc[t][ct][3];
            if (RELU) {
                a0 = fmaxf(a0, 0.f); a1 = fmaxf(a1, 0.f);
                a2 = fmaxf(a2, 0.f); a3 = fmaxf(a3, 0.f);
            }
            ushort4 pk;
            pk.x = f2bfu(a0); pk.y = f2bfu(a1); pk.z = f2bfu(a2); pk.w = f2bfu(a3);
            *reinterpret_cast<ushort4*>(
                ob + ((size_t)(t * 16 + lm) * COUT + ct * 16 + l4 * 4) * 2) = pk;
        }
}

// ---------------------------------------------------------------------------
// 2x2 maxpool NHWC 32ch (unchanged).
// ---------------------------------------------------------------------------
__global__ __launch_bounds__(256) void pool_k(
    const bf16* __restrict__ in, bf16* __restrict__ out)
{
    const int idx = blockIdx.x * 256 + threadIdx.x;
    const int c8 = (idx & 3) * 8;
    const int opx = idx >> 2;
    const int n = opx >> 16;
    const int p = opx & 65535;
    const int oy = p >> 8, ox = p & 255;
    const char* ip = (const char*)in
        + (((size_t)n * 262144 + (size_t)(2 * oy) * 512 + 2 * ox) * 32 + c8) * 2;
    uint4 ua = *reinterpret_cast<const uint4*>(ip);
    uint4 ub = *reinterpret_cast<const uint4*>(ip + 64);
    uint4 uc = *reinterpret_cast<const uint4*>(ip + 512 * 64);
    uint4 ud = *reinterpret_cast<const uint4*>(ip + 512 * 64 + 64);
    float a[8], b[8], c[8], d[8];
    unpk8(ua, a); unpk8(ub, b); unpk8(uc, c); unpk8(ud, d);
    unsigned short r[8];
    #pragma unroll
    for (int k = 0; k < 8; ++k)
        r[k] = f2bfu(fmaxf(fmaxf(a[k], b[k]), fmaxf(c[k], d[k])));
    __builtin_memcpy((char*)out + (((size_t)n * 65536 + p) * 32 + c8) * 2, r, 16);
}

// ---------------------------------------------------------------------------
// ConvT 2x2 s2 + skip add via MFMA (unchanged, R6).
// ---------------------------------------------------------------------------
__global__ __launch_bounds__(256) void convTm_k(
    const bf16* __restrict__ e, const bf16* __restrict__ wpT,
    const float* __restrict__ bt, bf16* __restrict__ du)
{
    __shared__ float lds[4][16 * 132];
    const int lane = threadIdx.x & 63;
    const int wv = threadIdx.x >> 6;
    const int l4 = lane >> 4, lm = lane & 15;
    const int n = blockIdx.y;
    const int row = blockIdx.x;
    const int j0 = wv * 64;

    bfrag8 afr[8];
    #pragma unroll
    for (int mt = 0; mt < 8; ++mt)
        __builtin_memcpy(&afr[mt], wpT + ((size_t)(mt * 64 + lane)) * 8, 16);

    float bco[8];
    #pragma unroll
    for (int mt = 0; mt < 8; ++mt) bco[mt] = bt[mt * 4 + l4];

    const char* ep = (const char*)e + ((size_t)n * 65536 + (size_t)row * 256 + j0) * 64;
    float* L = lds[wv];

    const int ra = lane >> 5;
    const int ru = lane & 31;
    const int rj = ru >> 1;
    const int rb = ru & 1;

    #pragma unroll 1
    for (int nt = 0; nt < 4; ++nt) {
        bfrag8 bf;
        __builtin_memcpy(&bf, ep + (nt * 16 + lm) * 64 + l4 * 16, 16);

        #pragma unroll
        for (int mt = 0; mt < 8; ++mt) {
            f32x4 acc;
            acc[0] = bco[mt]; acc[1] = bco[mt]; acc[2] = bco[mt]; acc[3] = bco[mt];
            acc = __builtin_amdgcn_mfma_f32_16x16x32_bf16(afr[mt], bf, acc, 0, 0, 0);
            float4 st; st.x = acc[0]; st.y = acc[1]; st.z = acc[2]; st.w = acc[3];
            *reinterpret_cast<float4*>(L + lm * 132 + mt * 16 + l4 * 4) = st;
        }
        __syncthreads();

        {
            const float* Ls = L + rj * 132 + ra * 2 + rb;
            char* dp = (char*)du
                + (((size_t)n * 262144
                    + (size_t)(2 * row + ra) * 512
                    + (size_t)(2 * (j0 + nt * 16 + rj) + rb)) * 32) * 2;
            float add[32];
            #pragma unroll
            for (int co = 0; co < 32; ++co) add[co] = Ls[co * 4];
            #pragma unroll
            for (int q = 0; q < 4; ++q) {
                uint4 u = *reinterpret_cast<const uint4*>(dp + q * 16);
                float dv[8]; unpk8(u, dv);
                unsigned short r[8];
                #pragma unroll
                for (int k = 0; k < 8; ++k) r[k] = f2bfu(dv[k] + add[q * 8 + k]);
                __builtin_memcpy(dp + q * 16, r, 16);
            }
        }
        __syncthreads();
    }
}

// ---------------------------------------------------------------------------
// S precompute: S(p) = sum_i cw_i * v_i(p)^2 over the 27 combined channels.
// ---------------------------------------------------------------------------
__global__ __launch_bounds__(256) void sprep_k(
    const float* __restrict__ xin, const bf16* __restrict__ feats,
    const float* __restrict__ fp, float* __restrict__ S)
{
    constexpr int PLANE = 512 * 512;
    const int pix = blockIdx.x * 256 + threadIdx.x;
    const int n = blockIdx.y;

    const float* xb = xin + (size_t)n * 16 * PLANE + pix;
    const char* fb = (const char*)feats + ((size_t)n * PLANE + pix) * 32;

    float s = 0.0f;
    #pragma unroll
    for (int i = 0; i < 11; ++i) {
        const float v = xb[(size_t)i * PLANE];
        s = fmaf(fp[i], v * v, s);
    }
    uint4 u0 = *reinterpret_cast<const uint4*>(fb);
    uint4 u1 = *reinterpret_cast<const uint4*>(fb + 16);
    float fv[16];
    unpk8(u0, fv); unpk8(u1, fv + 8);
    #pragma unroll
    for (int i = 0; i < 16; ++i)
        s = fmaf(fp[11 + i], fv[i] * fv[i], s);

    S[(size_t)n * PLANE + pix] = s;
}

// ---------------------------------------------------------------------------
// Bilateral, factored, y-PAIR: each thread computes centers (y0,x) and
// (y0+2,x). Tap rows y0+o, o in {-4..6 even}: rows -4..4 feed p0, -2..6 feed
// p1, middle 4 rows feed both (loads+unpack shared).
//   logw(p,q) = S_q - 2*sum_i g_i(p) v_i(q) + S_p + spatial
// ---------------------------------------------------------------------------
__global__ __launch_bounds__(256) void bil_k(
    const float* __restrict__ xin, const bf16* __restrict__ feats,
    const float* __restrict__ Sbuf, const float* __restrict__ fp,
    float* __restrict__ out)
{
    constexpr int PLANE = 512 * 512;
    const int n = blockIdx.y;
    const int rp = blockIdx.x >> 1;                       // row-pair 0..255
    const int xx = ((blockIdx.x & 1) << 8) + threadIdx.x; // 0..511
    const int y0 = ((rp >> 1) << 2) + (rp & 1);           // rows y0, y0+2

    const float sy = fp[27], sx = fp[28];

    const int p0 = y0 * 512 + xx;
    const float* xb = xin + (size_t)n * 16 * PLANE + p0;
    const char* fb = (const char*)feats + ((size_t)n * PLANE + p0) * 32;
    const float* Sb = Sbuf + (size_t)n * PLANE + p0;

    float g0[27], g1[27];
    #pragma unroll
    for (int i = 0; i < 11; ++i) {
        g0[i] = fp[i] * xb[(size_t)i * PLANE];
        g1[i] = fp[i] * xb[(size_t)i * PLANE + 1024];
    }
    {
        uint4 u0 = *reinterpret_cast<const uint4*>(fb);
        uint4 u1 = *reinterpret_cast<const uint4*>(fb + 16);
        float cf[16];
        unpk8(u0, cf); unpk8(u1, cf + 8);
        #pragma unroll
        for (int i = 0; i < 16; ++i) g0[11 + i] = fp[11 + i] * cf[i];
        u0 = *reinterpret_cast<const uint4*>(fb + 32768);
        u1 = *reinterpret_cast<const uint4*>(fb + 32768 + 16);
        unpk8(u0, cf); unpk8(u1, cf + 8);
        #pragma unroll
        for (int i = 0; i < 16; ++i) g1[11 + i] = fp[11 + i] * cf[i];
    }
    const float Sp0 = Sb[0];
    const float Sp1 = Sb[1024];

    float num0[11], num1[11];
    #pragma unroll
    for (int i = 0; i < 11; ++i) { num0[i] = 0.f; num1[i] = 0.f; }
    float den0 = 0.f, den1 = 0.f;

    #pragma unroll
    for (int o = -4; o <= 6; o += 2) {
        const int r = y0 + o;
        if ((unsigned)r > 511u) continue;                 // uniform per block
        const float b0 = fmaf(sy, (float)(o * o), Sp0);
        const float b1 = fmaf(sy, (float)((o - 2) * (o - 2)), Sp1);
        const float* xr = xb + o * 512;
        const char* fr = fb + (ptrdiff_t)o * 512 * 32;
        const float* Sr = Sb + o * 512;
        #pragma unroll
        for (int dx = -2; dx <= 2; ++dx) {
            const int xv = xx + 2 * dx;
            if ((unsigned)xv > 511u) continue;            // edge lanes only
            const int off = dx * 2;

            float sv[11];
            #pragma unroll
            for (int i = 0; i < 11; ++i) sv[i] = xr[(size_t)i * PLANE + off];
            uint4 u0 = *reinterpret_cast<const uint4*>(fr + off * 32);
            uint4 u1 = *reinterpret_cast<const uint4*>(fr + off * 32 + 16);
            float fv[16];
            unpk8(u0, fv); unpk8(u1, fv + 8);
            const float Sq = Sr[off] + sx * (float)(4 * dx * dx);

            if (o <= 4) {                                 // p0 tap
                float cr = g0[0] * sv[0];
                #pragma unroll
                for (int i = 1; i < 11; ++i) cr = fmaf(g0[i], sv[i], cr);
                #pragma unroll
                for (int i = 0; i < 16; ++i) cr = fmaf(g0[11 + i], fv[i], cr);
                const float w = __expf(fmaf(-2.0f, cr, Sq + b0));
                #pragma unroll
                for (int i = 0; i < 11; ++i) num0[i] = fmaf(w, sv[i], num0[i]);
                den0 += w;
            }
            if (o >= -2) {                                // p1 tap
                float cr = g1[0] * sv[0];
                #pragma unroll
                for (int i = 1; i < 11; ++i) cr = fmaf(g1[i], sv[i], cr);
                #pragma unroll
                for (int i = 0; i < 16; ++i) cr = fmaf(g1[11 + i], fv[i], cr);
                const float w = __expf(fmaf(-2.0f, cr, Sq + b1));
                #pragma unroll
                for (int i = 0; i < 11; ++i) num1[i] = fmaf(w, sv[i], num1[i]);
                den1 += w;
            }
        }
    }

    const float i0 = 1.f / den0, i1 = 1.f / den1;
    float* ob = out + (size_t)n * 11 * PLANE + p0;
    #pragma unroll
    for (int i = 0; i < 11; ++i) {
        ob[(size_t)i * PLANE] = num0[i] * i0;
        ob[(size_t)i * PLANE + 1024] = num1[i] * i1;
    }
}

// ---------------------------------------------------------------------------
extern "C" void kernel_launch(void* const* d_in, const int* in_sizes, int n_in,
                              void* d_out, int out_size, void* d_ws, size_t ws_size,
                              hipStream_t stream)
{
    const float* x = (const float*)d_in[0];
    const float* Wv[9];
    const float* Bv[9];
    if (in_sizes[2] == 16) {
        for (int i = 0; i < 9; ++i) {
            Wv[i] = (const float*)d_in[1 + 2 * i];
            Bv[i] = (const float*)d_in[2 + 2 * i];
        }
    } else {
        for (int i = 0; i < 9; ++i) {
            Wv[i] = (const float*)d_in[1 + i];
            Bv[i] = (const float*)d_in[10 + i];
        }
    }
    const float* wt = (const float*)d_in[19];
    const float* bt = (const float*)d_in[20];
    const float* fp = (const float*)d_in[21];
    float* out = (float*)d_out;

    constexpr size_t MiB = 1ull << 20;
    char* ws = (char*)d_ws;

    bf16* wp  = (bf16*)(ws + 4096);
    bf16* wpT = (bf16*)(ws + 256 * 1024);
    bf16 *xh, *du, *bufA, *bufB;
    if (ws_size >= 165 * MiB) {
        xh   = (bf16*)(ws + 1 * MiB);
        du   = (bf16*)(ws + 34 * MiB);
        bufA = (bf16*)(ws + 99 * MiB);
        bufB = (bf16*)(ws + 132 * MiB);
    } else if (ws_size >= 132 * MiB) {
        xh   = (bf16*)(ws + 1 * MiB);
        du   = (bf16*)(ws + 34 * MiB);
        bufA = (bf16*)(ws + 99 * MiB);
        bufB = xh;
    } else {
        xh   = (bf16*)((char*)d_out + 256);
        du   = (bf16*)(ws + 1 * MiB);
        bufA = (bf16*)(ws + 66 * MiB);
        bufB = xh;
    }
    float* Sbuf = (float*)du;   // du dead after conv6; reused for S (4 MiB)

    WSrc srcs;
    for (int i = 0; i < 9; ++i) srcs.w[i] = Wv[i];
    srcs.w[9] = wt;

    prep_k<<<10, 256, 0, stream>>>(srcs, wp, wpT);
    xtonhwc_k<<<4096, 256, 0, stream>>>(x, xh);

    const dim3 blk(256);
    const dim3 g512(1024, 4), g256(256, 4);

    convm_k<16, 16, true,  9><<<g512, blk, 0, stream>>>(xh,   wp + 0,     Bv[0], bufA);
    convm_k<16, 16, true,  9><<<g512, blk, 0, stream>>>(bufA, wp + 3072,  Bv[1], bufB);
    convm_k<16, 32, false, 9><<<g512, blk, 0, stream>>>(bufB, wp + 6144,  Bv[2], du);

    pool_k<<<4096, blk, 0, stream>>>(du, bufA);
    convm_k<32, 32, true, 8><<<g256, blk, 0, stream>>>(bufA, wp + 12288, Bv[3], bufB);
    convm_k<32, 32, true, 8><<<g256, blk, 0, stream>>>(bufB, wp + 21504, Bv[4], bufA);
    convm_k<32, 32, true, 8><<<g256, blk, 0, stream>>>(bufA, wp + 30720, Bv[5], bufB);

    convTm_k<<<g256, blk, 0, stream>>>(bufB, wpT, bt, du);

    convm_k<32, 16, true,  9><<<g512, blk, 0, stream>>>(du,   wp + 39936, Bv[6], bufA);
    convm_k<16, 16, true,  9><<<g512, blk, 0, stream>>>(bufA, wp + 44544, Bv[7], bufB);
    convm_k<16, 16, false, 9><<<g512, blk, 0, stream>>>(bufB, wp + 47616, Bv[8], bufA);

    // S plane (du region, dead now), then y-paired factored bilateral
    sprep_k<<<g512, blk, 0, stream>>>(x, bufA, fp, Sbuf);
    bil_k<<<dim3(512, 4), blk, 0, stream>>>(x, bufA, Sbuf, fp, out);

    (void)n_in; (void)out_size;
}

// Round 10
// 393.676 us; speedup vs baseline: 1.1910x; 1.1086x over previous
//
#include <hip/hip_runtime.h>
#include <hip/hip_bf16.h>
#include <cstdint>
#include <cstddef>

typedef __hip_bfloat16 bf16;
typedef __attribute__((ext_vector_type(8))) short bfrag8;   // 8 bf16 = 4 VGPR
typedef __attribute__((ext_vector_type(4))) float f32x4;    // MFMA acc

// ---- bf16 bit helpers ------------------------------------------------------
__device__ __forceinline__ float bfu2f(unsigned int u16) {
    unsigned int w = u16 << 16;
    float f; __builtin_memcpy(&f, &w, 4); return f;
}
__device__ __forceinline__ float bfhi2f(unsigned int u) {      // high half as-is
    unsigned int w = u & 0xffff0000u;
    float f; __builtin_memcpy(&f, &w, 4); return f;
}
__device__ __forceinline__ unsigned short f2bfu(float f) {
    bf16 h = __float2bfloat16(f);
    unsigned short u; __builtin_memcpy(&u, &h, 2); return u;
}
__device__ __forceinline__ void unpk8(const uint4 u, float* f) {
    f[0] = bfu2f(u.x); f[1] = bfhi2f(u.x);
    f[2] = bfu2f(u.y); f[3] = bfhi2f(u.y);
    f[4] = bfu2f(u.z); f[5] = bfhi2f(u.z);
    f[6] = bfu2f(u.w); f[7] = bfhi2f(u.w);
}

// ---------------------------------------------------------------------------
// Weight prep: OIHW f32 -> MFMA A-fragment bf16 (blocks 0..8 = convs,
// block 9 = convT weights, m = co*4 + a*2 + b, k = ci).
// ---------------------------------------------------------------------------
struct WSrc { const float* w[10]; };

__global__ __launch_bounds__(256) void prep_k(WSrc src, bf16* __restrict__ wp,
                                              bf16* __restrict__ wpT) {
    const int l = blockIdx.x;
    if (l == 9) {
        const float* wt = src.w[9];
        for (int e = threadIdx.x; e < 4096; e += 256) {
            const int j = e & 7;
            const int lane = (e >> 3) & 63;
            const int mt = e >> 9;
            const int m = mt * 16 + (lane & 15);
            const int k = ((lane >> 4) << 3) + j;     // ci
            wpT[e] = __float2bfloat16(wt[k * 128 + m]);
        }
        return;
    }
    const int CI[9]  = {16, 16, 16, 32, 32, 32, 32, 16, 16};
    const int CO[9]  = {16, 16, 32, 32, 32, 32, 16, 16, 16};
    const int OFF[9] = {0, 3072, 6144, 12288, 21504, 30720, 39936, 44544, 47616};
    const int cin = CI[l], cout = CO[l], nct = cout / 16;
    const int nt = (cin == 32) ? 9 : 6;
    const int sz = nt * nct * 512;
    const float* w = src.w[l];
    bf16* dst = wp + OFF[l];
    for (int e = threadIdx.x; e < sz; e += 256) {
        const int j = e & 7;
        const int lane = (e >> 3) & 63;
        const int r = e >> 9;
        const int ct = r % nct, tp = r / nct;
        const int co = ct * 16 + (lane & 15);
        const int kk = ((lane >> 4) << 3) + j;
        float v;
        if (cin == 32) {
            const int ci = kk, ky = tp / 3, kx = tp % 3;
            v = w[((co * 32 + ci) * 3 + ky) * 3 + kx];
        } else {
            const int ci = kk & 15, dxs = kk >> 4;
            const int ky = tp >> 1, kx = (tp & 1) * 2 + dxs;
            v = (kx < 3) ? w[((co * 16 + ci) * 3 + ky) * 3 + kx] : 0.0f;
        }
        dst[e] = __float2bfloat16(v);
    }
}

// ---------------------------------------------------------------------------
// x (NCHW f32, 16ch) -> NHWC bf16
// ---------------------------------------------------------------------------
__global__ __launch_bounds__(256) void xtonhwc_k(
    const float* __restrict__ x, bf16* __restrict__ xh)
{
    const int idx = blockIdx.x * 256 + threadIdx.x;   // 4*262144
    const int n = idx >> 18, px = idx & 262143;
    const float* xp = x + (size_t)n * 16 * 262144 + px;
    unsigned short r[16];
    #pragma unroll
    for (int c = 0; c < 16; ++c) r[c] = f2bfu(xp[(size_t)c * 262144]);
    __builtin_memcpy(xh + (size_t)idx * 16, r, 32);
}

// ---------------------------------------------------------------------------
// Implicit-GEMM 3x3 conv, 2-ROW wave blocking, 512x512 only.
// Wave computes rows (y0, y0+1) x 64 cols; tap rows y0-1..y0+2 loaded ONCE
// and consumed by both output rows (loads/output-row: 24->16 CIN16, 36->24
// CIN32; MFMA count unchanged).
// ---------------------------------------------------------------------------
template<int CIN, int COUT, bool RELU>
__global__ __launch_bounds__(256) void convm2_k(
    const bf16* __restrict__ in, const bf16* __restrict__ wp,
    const float* __restrict__ bias, bf16* __restrict__ out)
{
    constexpr int Wd = 512;
    constexpr int PLANE = Wd * Wd;
    constexpr int NCT = COUT / 16;
    constexpr int NT = (CIN == 32) ? 9 : 6;
    constexpr int CB = CIN * 2;

    const int lane = threadIdx.x & 63;
    const int l4 = lane >> 4;
    const int lm = lane & 15;
    const int wv = threadIdx.x >> 6;
    const int n = blockIdx.y;
    const int y0 = (blockIdx.x >> 1) * 2;                  // row pair
    const int xw = (blockIdx.x & 1) * 256 + wv * 64;       // wave col base

    bfrag8 afr[NT][NCT];
    #pragma unroll
    for (int tp = 0; tp < NT; ++tp)
        #pragma unroll
        for (int ct = 0; ct < NCT; ++ct)
            __builtin_memcpy(&afr[tp][ct],
                wp + ((size_t)(tp * NCT + ct) * 64 + lane) * 8, 16);

    f32x4 acc[2][4][NCT];
    #pragma unroll
    for (int ct = 0; ct < NCT; ++ct) {
        const float4 bv = *reinterpret_cast<const float4*>(bias + ct * 16 + l4 * 4);
        #pragma unroll
        for (int o = 0; o < 2; ++o)
            #pragma unroll
            for (int t = 0; t < 4; ++t) {
                acc[o][t][ct][0] = bv.x; acc[o][t][ct][1] = bv.y;
                acc[o][t][ct][2] = bv.z; acc[o][t][ct][3] = bv.w;
            }
    }

    bool okL[4], okR[4];
    #pragma unroll
    for (int t = 0; t < 4; ++t) {
        const int xl = xw + t * 16 + lm;
        okL[t] = (xl != 0)      || (CIN == 16 && lane >= 32);
        okR[t] = (xl != Wd - 1) || (CIN == 16 && lane >= 32);
    }

    int laneoff;
    if (CIN == 32) laneoff = lm * 64 + l4 * 16;
    else           laneoff = lm * 32 + (l4 >> 1) * 32 + (l4 & 1) * 16;

    const char* base = (const char*)in
        + ((size_t)n * PLANE + (size_t)y0 * Wd + xw) * CB + laneoff;

    #pragma unroll
    for (int r = 0; r < 4; ++r) {                  // tap row y0-1+r
        const int ry = y0 - 1 + r;
        if ((unsigned)ry >= (unsigned)Wd) continue;   // uniform per block
        const char* rb = base + (r - 1) * Wd * CB;
        if (CIN == 32) {
            #pragma unroll
            for (int dx = 0; dx < 3; ++dx)
                #pragma unroll
                for (int t = 0; t < 4; ++t) {
                    uint4 u = *reinterpret_cast<const uint4*>(rb + ((dx - 1) + t * 16) * 64);
                    if (dx == 0 && !okL[t]) { u.x = 0; u.y = 0; u.z = 0; u.w = 0; }
                    if (dx == 2 && !okR[t]) { u.x = 0; u.y = 0; u.z = 0; u.w = 0; }
                    bfrag8 b; __builtin_memcpy(&b, &u, 16);
                    if (r <= 2)                       // out row y0, ky=r
                        #pragma unroll
                        for (int ct = 0; ct < NCT; ++ct)
                            acc[0][t][ct] = __builtin_amdgcn_mfma_f32_16x16x32_bf16(
                                afr[r * 3 + dx][ct], b, acc[0][t][ct], 0, 0, 0);
                    if (r >= 1)                       // out row y0+1, ky=r-1
                        #pragma unroll
                        for (int ct = 0; ct < NCT; ++ct)
                            acc[1][t][ct] = __builtin_amdgcn_mfma_f32_16x16x32_bf16(
                                afr[(r - 1) * 3 + dx][ct], b, acc[1][t][ct], 0, 0, 0);
                }
        } else {
            #pragma unroll
            for (int p = 0; p < 2; ++p)
                #pragma unroll
                for (int t = 0; t < 4; ++t) {
                    uint4 u = *reinterpret_cast<const uint4*>(rb + (p ? 32 : -32) + t * 512);
                    if (p == 0 && !okL[t]) { u.x = 0; u.y = 0; u.z = 0; u.w = 0; }
                    if (p == 1 && !okR[t]) { u.x = 0; u.y = 0; u.z = 0; u.w = 0; }
                    bfrag8 b; __builtin_memcpy(&b, &u, 16);
                    if (r <= 2)
                        #pragma unroll
                        for (int ct = 0; ct < NCT; ++ct)
                            acc[0][t][ct] = __builtin_amdgcn_mfma_f32_16x16x32_bf16(
                                afr[r * 2 + p][ct], b, acc[0][t][ct], 0, 0, 0);
                    if (r >= 1)
                        #pragma unroll
                        for (int ct = 0; ct < NCT; ++ct)
                            acc[1][t][ct] = __builtin_amdgcn_mfma_f32_16x16x32_bf16(
                                afr[(r - 1) * 2 + p][ct], b, acc[1][t][ct], 0, 0, 0);
                }
        }
    }

    #pragma unroll
    for (int o = 0; o < 2; ++o) {
        char* ob = (char*)out
            + ((size_t)n * PLANE + (size_t)(y0 + o) * Wd + xw) * (COUT * 2);
        #pragma unroll
        for (int t = 0; t < 4; ++t)
            #pragma unroll
            for (int ct = 0; ct < NCT; ++ct) {
                float a0 = acc[o][t][ct][0], a1 = acc[o][t][ct][1];
                float a2 = acc[o][t][ct][2], a3 = acc[o][t][ct][3];
                if (RELU) {
                    a0 = fmaxf(a0, 0.f); a1 = fmaxf(a1, 0.f);
                    a2 = fmaxf(a2, 0.f); a3 = fmaxf(a3, 0.f);
                }
                ushort4 pk;
                pk.x = f2bfu(a0); pk.y = f2bfu(a1); pk.z = f2bfu(a2); pk.w = f2bfu(a3);
                *reinterpret_cast<ushort4*>(
                    ob + ((size_t)(t * 16 + lm) * COUT + ct * 16 + l4 * 4) * 2) = pk;
            }
    }
}

// ---------------------------------------------------------------------------
// Implicit-GEMM 3x3 conv (1-row), used for 256x256 stages (unchanged).
// ---------------------------------------------------------------------------
template<int CIN, int COUT, bool RELU, int LW>
__global__ __launch_bounds__(256) void convm_k(
    const bf16* __restrict__ in, const bf16* __restrict__ wp,
    const float* __restrict__ bias, bf16* __restrict__ out)
{
    constexpr int Wd = 1 << LW;
    constexpr int PLANE = Wd * Wd;
    constexpr int NCT = COUT / 16;
    constexpr int NT = (CIN == 32) ? 9 : 6;
    constexpr int CB = CIN * 2;

    const int lane = threadIdx.x & 63;
    const int l4 = lane >> 4;
    const int lm = lane & 15;
    const int wv = threadIdx.x >> 6;
    const int n = blockIdx.y;
    const int pxb = blockIdx.x * 256 + wv * 64;
    const int y = pxb >> LW;
    const int xw = pxb & (Wd - 1);

    bfrag8 afr[NT][NCT];
    #pragma unroll
    for (int tp = 0; tp < NT; ++tp)
        #pragma unroll
        for (int ct = 0; ct < NCT; ++ct)
            __builtin_memcpy(&afr[tp][ct],
                wp + ((size_t)(tp * NCT + ct) * 64 + lane) * 8, 16);

    f32x4 acc[4][NCT];
    #pragma unroll
    for (int ct = 0; ct < NCT; ++ct) {
        const float4 bv = *reinterpret_cast<const float4*>(bias + ct * 16 + l4 * 4);
        #pragma unroll
        for (int t = 0; t < 4; ++t) {
            acc[t][ct][0] = bv.x; acc[t][ct][1] = bv.y;
            acc[t][ct][2] = bv.z; acc[t][ct][3] = bv.w;
        }
    }

    bool okL[4], okR[4];
    #pragma unroll
    for (int t = 0; t < 4; ++t) {
        const int xl = xw + t * 16 + lm;
        okL[t] = (xl != 0)      || (CIN == 16 && lane >= 32);
        okR[t] = (xl != Wd - 1) || (CIN == 16 && lane >= 32);
    }

    int laneoff;
    if (CIN == 32) laneoff = lm * 64 + l4 * 16;
    else           laneoff = lm * 32 + (l4 >> 1) * 32 + (l4 & 1) * 16;

    const char* base = (const char*)in
        + ((size_t)n * PLANE + (size_t)y * Wd + xw) * CB + laneoff;

    #pragma unroll
    for (int ky = 0; ky < 3; ++ky) {
        if ((unsigned)(y + ky - 1) >= (unsigned)Wd) continue;
        const char* rb = base + (ky - 1) * Wd * CB;
        if (CIN == 32) {
            #pragma unroll
            for (int dx = 0; dx < 3; ++dx) {
                #pragma unroll
                for (int t = 0; t < 4; ++t) {
                    uint4 u = *reinterpret_cast<const uint4*>(rb + ((dx - 1) + t * 16) * 64);
                    if (dx == 0 && !okL[t]) { u.x = 0; u.y = 0; u.z = 0; u.w = 0; }
                    if (dx == 2 && !okR[t]) { u.x = 0; u.y = 0; u.z = 0; u.w = 0; }
                    bfrag8 b; __builtin_memcpy(&b, &u, 16);
                    #pragma unroll
                    for (int ct = 0; ct < NCT; ++ct)
                        acc[t][ct] = __builtin_amdgcn_mfma_f32_16x16x32_bf16(
                            afr[ky * 3 + dx][ct], b, acc[t][ct], 0, 0, 0);
                }
            }
        } else {
            #pragma unroll
            for (int p = 0; p < 2; ++p) {
                #pragma unroll
                for (int t = 0; t < 4; ++t) {
                    uint4 u = *reinterpret_cast<const uint4*>(rb + (p ? 32 : -32) + t * 512);
                    if (p == 0 && !okL[t]) { u.x = 0; u.y = 0; u.z = 0; u.w = 0; }
                    if (p == 1 && !okR[t]) { u.x = 0; u.y = 0; u.z = 0; u.w = 0; }
                    bfrag8 b; __builtin_memcpy(&b, &u, 16);
                    #pragma unroll
                    for (int ct = 0; ct < NCT; ++ct)
                        acc[t][ct] = __builtin_amdgcn_mfma_f32_16x16x32_bf16(
                            afr[ky * 2 + p][ct], b, acc[t][ct], 0, 0, 0);
                }
            }
        }
    }

    char* ob = (char*)out + ((size_t)n * PLANE + (size_t)y * Wd + xw) * (COUT * 2);
    #pragma unroll
    for (int t = 0; t < 4; ++t)
        #pragma unroll
        for (int ct = 0; ct < NCT; ++ct) {
            float a0 = acc[t][ct][0], a1 = acc[t][ct][1];
            float a2 = acc[t][ct][2], a3 = acc[t][ct][3];
            if (RELU) {
                a0 = fmaxf(a0, 0.f); a1 = fmaxf(a1, 0.f);
                a2 = fmaxf(a2, 0.f); a3 = fmaxf(a3, 0.f);
            }
            ushort4 pk;
            pk.x = f2bfu(a0); pk.y = f2bfu(a1); pk.z = f2bfu(a2); pk.w = f2bfu(a3);
            *reinterpret_cast<ushort4*>(
                ob + ((size_t)(t * 16 + lm) * COUT + ct * 16 + l4 * 4) * 2) = pk;
        }
}

// ---------------------------------------------------------------------------
// 2x2 maxpool NHWC 32ch (unchanged).
// ---------------------------------------------------------------------------
__global__ __launch_bounds__(256) void pool_k(
    const bf16* __restrict__ in, bf16* __restrict__ out)
{
    const int idx = blockIdx.x * 256 + threadIdx.x;
    const int c8 = (idx & 3) * 8;
    const int opx = idx >> 2;
    const int n = opx >> 16;
    const int p = opx & 65535;
    const int oy = p >> 8, ox = p & 255;
    const char* ip = (const char*)in
        + (((size_t)n * 262144 + (size_t)(2 * oy) * 512 + 2 * ox) * 32 + c8) * 2;
    uint4 ua = *reinterpret_cast<const uint4*>(ip);
    uint4 ub = *reinterpret_cast<const uint4*>(ip + 64);
    uint4 uc = *reinterpret_cast<const uint4*>(ip + 512 * 64);
    uint4 ud = *reinterpret_cast<const uint4*>(ip + 512 * 64 + 64);
    float a[8], b[8], c[8], d[8];
    unpk8(ua, a); unpk8(ub, b); unpk8(uc, c); unpk8(ud, d);
    unsigned short r[8];
    #pragma unroll
    for (int k = 0; k < 8; ++k)
        r[k] = f2bfu(fmaxf(fmaxf(a[k], b[k]), fmaxf(c[k], d[k])));
    __builtin_memcpy((char*)out + (((size_t)n * 65536 + p) * 32 + c8) * 2, r, 16);
}

// ---------------------------------------------------------------------------
// ConvT 2x2 s2 + skip add via MFMA (unchanged).
// ---------------------------------------------------------------------------
__global__ __launch_bounds__(256) void convTm_k(
    const bf16* __restrict__ e, const bf16* __restrict__ wpT,
    const float* __restrict__ bt, bf16* __restrict__ du)
{
    __shared__ float lds[4][16 * 132];
    const int lane = threadIdx.x & 63;
    const int wv = threadIdx.x >> 6;
    const int l4 = lane >> 4, lm = lane & 15;
    const int n = blockIdx.y;
    const int row = blockIdx.x;
    const int j0 = wv * 64;

    bfrag8 afr[8];
    #pragma unroll
    for (int mt = 0; mt < 8; ++mt)
        __builtin_memcpy(&afr[mt], wpT + ((size_t)(mt * 64 + lane)) * 8, 16);

    float bco[8];
    #pragma unroll
    for (int mt = 0; mt < 8; ++mt) bco[mt] = bt[mt * 4 + l4];

    const char* ep = (const char*)e + ((size_t)n * 65536 + (size_t)row * 256 + j0) * 64;
    float* L = lds[wv];

    const int ra = lane >> 5;
    const int ru = lane & 31;
    const int rj = ru >> 1;
    const int rb = ru & 1;

    #pragma unroll 1
    for (int nt = 0; nt < 4; ++nt) {
        bfrag8 bf;
        __builtin_memcpy(&bf, ep + (nt * 16 + lm) * 64 + l4 * 16, 16);

        #pragma unroll
        for (int mt = 0; mt < 8; ++mt) {
            f32x4 acc;
            acc[0] = bco[mt]; acc[1] = bco[mt]; acc[2] = bco[mt]; acc[3] = bco[mt];
            acc = __builtin_amdgcn_mfma_f32_16x16x32_bf16(afr[mt], bf, acc, 0, 0, 0);
            float4 st; st.x = acc[0]; st.y = acc[1]; st.z = acc[2]; st.w = acc[3];
            *reinterpret_cast<float4*>(L + lm * 132 + mt * 16 + l4 * 4) = st;
        }
        __syncthreads();

        {
            const float* Ls = L + rj * 132 + ra * 2 + rb;
            char* dp = (char*)du
                + (((size_t)n * 262144
                    + (size_t)(2 * row + ra) * 512
                    + (size_t)(2 * (j0 + nt * 16 + rj) + rb)) * 32) * 2;
            float add[32];
            #pragma unroll
            for (int co = 0; co < 32; ++co) add[co] = Ls[co * 4];
            #pragma unroll
            for (int q = 0; q < 4; ++q) {
                uint4 u = *reinterpret_cast<const uint4*>(dp + q * 16);
                float dv[8]; unpk8(u, dv);
                unsigned short r[8];
                #pragma unroll
                for (int k = 0; k < 8; ++k) r[k] = f2bfu(dv[k] + add[q * 8 + k]);
                __builtin_memcpy(dp + q * 16, r, 16);
            }
        }
        __syncthreads();
    }
}

// ---------------------------------------------------------------------------
// S precompute: S(p) = sum_i cw_i * v_i(p)^2 over the 27 combined channels.
// ---------------------------------------------------------------------------
__global__ __launch_bounds__(256) void sprep_k(
    const float* __restrict__ xin, const bf16* __restrict__ feats,
    const float* __restrict__ fp, float* __restrict__ S)
{
    constexpr int PLANE = 512 * 512;
    const int pix = blockIdx.x * 256 + threadIdx.x;
    const int n = blockIdx.y;

    const float* xb = xin + (size_t)n * 16 * PLANE + pix;
    const char* fb = (const char*)feats + ((size_t)n * PLANE + pix) * 32;

    float s = 0.0f;
    #pragma unroll
    for (int i = 0; i < 11; ++i) {
        const float v = xb[(size_t)i * PLANE];
        s = fmaf(fp[i], v * v, s);
    }
    uint4 u0 = *reinterpret_cast<const uint4*>(fb);
    uint4 u1 = *reinterpret_cast<const uint4*>(fb + 16);
    float fv[16];
    unpk8(u0, fv); unpk8(u1, fv + 8);
    #pragma unroll
    for (int i = 0; i < 16; ++i)
        s = fmaf(fp[11 + i], fv[i] * fv[i], s);

    S[(size_t)n * PLANE + pix] = s;
}

// ---------------------------------------------------------------------------
// Bilateral, factored, y-PAIR (unchanged, R9).
// ---------------------------------------------------------------------------
__global__ __launch_bounds__(256) void bil_k(
    const float* __restrict__ xin, const bf16* __restrict__ feats,
    const float* __restrict__ Sbuf, const float* __restrict__ fp,
    float* __restrict__ out)
{
    constexpr int PLANE = 512 * 512;
    const int n = blockIdx.y;
    const int rp = blockIdx.x >> 1;                       // row-pair 0..255
    const int xx = ((blockIdx.x & 1) << 8) + threadIdx.x; // 0..511
    const int y0 = ((rp >> 1) << 2) + (rp & 1);           // rows y0, y0+2

    const float sy = fp[27], sx = fp[28];

    const int p0 = y0 * 512 + xx;
    const float* xb = xin + (size_t)n * 16 * PLANE + p0;
    const char* fb = (const char*)feats + ((size_t)n * PLANE + p0) * 32;
    const float* Sb = Sbuf + (size_t)n * PLANE + p0;

    float g0[27], g1[27];
    #pragma unroll
    for (int i = 0; i < 11; ++i) {
        g0[i] = fp[i] * xb[(size_t)i * PLANE];
        g1[i] = fp[i] * xb[(size_t)i * PLANE + 1024];
    }
    {
        uint4 u0 = *reinterpret_cast<const uint4*>(fb);
        uint4 u1 = *reinterpret_cast<const uint4*>(fb + 16);
        float cf[16];
        unpk8(u0, cf); unpk8(u1, cf + 8);
        #pragma unroll
        for (int i = 0; i < 16; ++i) g0[11 + i] = fp[11 + i] * cf[i];
        u0 = *reinterpret_cast<const uint4*>(fb + 32768);
        u1 = *reinterpret_cast<const uint4*>(fb + 32768 + 16);
        unpk8(u0, cf); unpk8(u1, cf + 8);
        #pragma unroll
        for (int i = 0; i < 16; ++i) g1[11 + i] = fp[11 + i] * cf[i];
    }
    const float Sp0 = Sb[0];
    const float Sp1 = Sb[1024];

    float num0[11], num1[11];
    #pragma unroll
    for (int i = 0; i < 11; ++i) { num0[i] = 0.f; num1[i] = 0.f; }
    float den0 = 0.f, den1 = 0.f;

    #pragma unroll
    for (int o = -4; o <= 6; o += 2) {
        const int r = y0 + o;
        if ((unsigned)r > 511u) continue;                 // uniform per block
        const float b0 = fmaf(sy, (float)(o * o), Sp0);
        const float b1 = fmaf(sy, (float)((o - 2) * (o - 2)), Sp1);
        const float* xr = xb + o * 512;
        const char* fr = fb + (ptrdiff_t)o * 512 * 32;
        const float* Sr = Sb + o * 512;
        #pragma unroll
        for (int dx = -2; dx <= 2; ++dx) {
            const int xv = xx + 2 * dx;
            if ((unsigned)xv > 511u) continue;            // edge lanes only
            const int off = dx * 2;

            float sv[11];
            #pragma unroll
            for (int i = 0; i < 11; ++i) sv[i] = xr[(size_t)i * PLANE + off];
            uint4 u0 = *reinterpret_cast<const uint4*>(fr + off * 32);
            uint4 u1 = *reinterpret_cast<const uint4*>(fr + off * 32 + 16);
            float fv[16];
            unpk8(u0, fv); unpk8(u1, fv + 8);
            const float Sq = Sr[off] + sx * (float)(4 * dx * dx);

            if (o <= 4) {                                 // p0 tap
                float cr = g0[0] * sv[0];
                #pragma unroll
                for (int i = 1; i < 11; ++i) cr = fmaf(g0[i], sv[i], cr);
                #pragma unroll
                for (int i = 0; i < 16; ++i) cr = fmaf(g0[11 + i], fv[i], cr);
                const float w = __expf(fmaf(-2.0f, cr, Sq + b0));
                #pragma unroll
                for (int i = 0; i < 11; ++i) num0[i] = fmaf(w, sv[i], num0[i]);
                den0 += w;
            }
            if (o >= -2) {                                // p1 tap
                float cr = g1[0] * sv[0];
                #pragma unroll
                for (int i = 1; i < 11; ++i) cr = fmaf(g1[i], sv[i], cr);
                #pragma unroll
                for (int i = 0; i < 16; ++i) cr = fmaf(g1[11 + i], fv[i], cr);
                const float w = __expf(fmaf(-2.0f, cr, Sq + b1));
                #pragma unroll
                for (int i = 0; i < 11; ++i) num1[i] = fmaf(w, sv[i], num1[i]);
                den1 += w;
            }
        }
    }

    const float i0 = 1.f / den0, i1 = 1.f / den1;
    float* ob = out + (size_t)n * 11 * PLANE + p0;
    #pragma unroll
    for (int i = 0; i < 11; ++i) {
        ob[(size_t)i * PLANE] = num0[i] * i0;
        ob[(size_t)i * PLANE + 1024] = num1[i] * i1;
    }
}

// ---------------------------------------------------------------------------
extern "C" void kernel_launch(void* const* d_in, const int* in_sizes, int n_in,
                              void* d_out, int out_size, void* d_ws, size_t ws_size,
                              hipStream_t stream)
{
    const float* x = (const float*)d_in[0];
    const float* Wv[9];
    const float* Bv[9];
    if (in_sizes[2] == 16) {
        for (int i = 0; i < 9; ++i) {
            Wv[i] = (const float*)d_in[1 + 2 * i];
            Bv[i] = (const float*)d_in[2 + 2 * i];
        }
    } else {
        for (int i = 0; i < 9; ++i) {
            Wv[i] = (const float*)d_in[1 + i];
            Bv[i] = (const float*)d_in[10 + i];
        }
    }
    const float* wt = (const float*)d_in[19];
    const float* bt = (const float*)d_in[20];
    const float* fp = (const float*)d_in[21];
    float* out = (float*)d_out;

    constexpr size_t MiB = 1ull << 20;
    char* ws = (char*)d_ws;

    bf16* wp  = (bf16*)(ws + 4096);
    bf16* wpT = (bf16*)(ws + 256 * 1024);
    bf16 *xh, *du, *bufA, *bufB;
    if (ws_size >= 165 * MiB) {
        xh   = (bf16*)(ws + 1 * MiB);
        du   = (bf16*)(ws + 34 * MiB);
        bufA = (bf16*)(ws + 99 * MiB);
        bufB = (bf16*)(ws + 132 * MiB);
    } else if (ws_size >= 132 * MiB) {
        xh   = (bf16*)(ws + 1 * MiB);
        du   = (bf16*)(ws + 34 * MiB);
        bufA = (bf16*)(ws + 99 * MiB);
        bufB = xh;
    } else {
        xh   = (bf16*)((char*)d_out + 256);
        du   = (bf16*)(ws + 1 * MiB);
        bufA = (bf16*)(ws + 66 * MiB);
        bufB = xh;
    }
    float* Sbuf = (float*)du;   // du dead after conv6; reused for S (4 MiB)

    WSrc srcs;
    for (int i = 0; i < 9; ++i) srcs.w[i] = Wv[i];
    srcs.w[9] = wt;

    prep_k<<<10, 256, 0, stream>>>(srcs, wp, wpT);
    xtonhwc_k<<<4096, 256, 0, stream>>>(x, xh);

    const dim3 blk(256);
    const dim3 g512(512, 4);    // 2-row conv blocks: 256 pairs x 2 col halves
    const dim3 gpix(1024, 4);   // 1px/thread 512^2 kernels
    const dim3 g256(256, 4);

    convm2_k<16, 16, true ><<<g512, blk, 0, stream>>>(xh,   wp + 0,     Bv[0], bufA);
    convm2_k<16, 16, true ><<<g512, blk, 0, stream>>>(bufA, wp + 3072,  Bv[1], bufB);
    convm2_k<16, 32, false><<<g512, blk, 0, stream>>>(bufB, wp + 6144,  Bv[2], du);

    pool_k<<<4096, blk, 0, stream>>>(du, bufA);
    convm_k<32, 32, true, 8><<<g256, blk, 0, stream>>>(bufA, wp + 12288, Bv[3], bufB);
    convm_k<32, 32, true, 8><<<g256, blk, 0, stream>>>(bufB, wp + 21504, Bv[4], bufA);
    convm_k<32, 32, true, 8><<<g256, blk, 0, stream>>>(bufA, wp + 30720, Bv[5], bufB);

    convTm_k<<<g256, blk, 0, stream>>>(bufB, wpT, bt, du);

    convm2_k<32, 16, true ><<<g512, blk, 0, stream>>>(du,   wp + 39936, Bv[6], bufA);
    convm2_k<16, 16, true ><<<g512, blk, 0, stream>>>(bufA, wp + 44544, Bv[7], bufB);
    convm2_k<16, 16, false><<<g512, blk, 0, stream>>>(bufB, wp + 47616, Bv[8], bufA);

    // S plane (du region, dead now), then y-paired factored bilateral
    sprep_k<<<gpix, blk, 0, stream>>>(x, bufA, fp, Sbuf);
    bil_k<<<dim3(512, 4), blk, 0, stream>>>(x, bufA, Sbuf, fp, out);

    (void)n_in; (void)out_size;
}